// Round 1
// baseline (202.680 us; speedup 1.0000x reference)
//
#include <hip/hip_runtime.h>

#define DIM 64

// Kernel 1: zW = z @ W.  W staged in LDS; each wave computes 16 rows,
// lane j produces column j.  sW[k*64+lane] -> 2-way bank aliasing (free).
__global__ __launch_bounds__(256) void zw_gemm_kernel(
    const float* __restrict__ z, const float* __restrict__ W,
    float* __restrict__ zW, int n_nodes) {
    __shared__ float sW[DIM * DIM];
    // Load W (4096 floats) cooperatively as float4.
    const float4* W4 = (const float4*)W;
    float4* sW4 = (float4*)sW;
    for (int i = threadIdx.x; i < DIM * DIM / 4; i += 256) sW4[i] = W4[i];
    __syncthreads();

    const int wave = threadIdx.x >> 6;   // 0..3
    const int lane = threadIdx.x & 63;   // output column
    const int rowBase = blockIdx.x * 64 + wave * 16;

    for (int i = 0; i < 16; ++i) {
        const int row = rowBase + i;
        if (row >= n_nodes) return;      // wave-uniform branch
        const float* zrow = z + (size_t)row * DIM;
        float acc = 0.f;
#pragma unroll
        for (int k = 0; k < DIM; k += 4) {
            // contiguous -> compiler emits dwordx4; same addr across lanes -> broadcast
            float4 zv = *(const float4*)(zrow + k);
            acc += zv.x * sW[(k + 0) * DIM + lane];
            acc += zv.y * sW[(k + 1) * DIM + lane];
            acc += zv.z * sW[(k + 2) * DIM + lane];
            acc += zv.w * sW[(k + 3) * DIM + lane];
        }
        zW[(size_t)row * DIM + lane] = acc;
    }
}

// Kernel 2: 16 lanes per edge.  Each 16-lane group reads one 256B zW row and
// one 256B z row fully coalesced (float4/lane), dot4 + 4-step shfl_xor reduce.
__global__ __launch_bounds__(256) void edge_score_kernel(
    const float* __restrict__ zW, const float* __restrict__ z,
    const int* __restrict__ edge_index, const float* __restrict__ bias,
    float* __restrict__ out, int n_edges) {
    const int t = blockIdx.x * 256 + threadIdx.x;
    const int edge = t >> 4;
    const int sub = t & 15;
    if (edge >= n_edges) return;

    const int src = edge_index[edge];             // row 0 of edge_index
    const int dst = edge_index[n_edges + edge];   // row 1

    float4 a = ((const float4*)(zW + (size_t)src * DIM))[sub];
    float4 b = ((const float4*)(z  + (size_t)dst * DIM))[sub];
    float p = a.x * b.x + a.y * b.y + a.z * b.z + a.w * b.w;

    // xor masks 1,2,4,8 stay within each 16-lane group of the 64-lane wave
    p += __shfl_xor(p, 1);
    p += __shfl_xor(p, 2);
    p += __shfl_xor(p, 4);
    p += __shfl_xor(p, 8);

    if (sub == 0) out[edge] = p + bias[0];
}

extern "C" void kernel_launch(void* const* d_in, const int* in_sizes, int n_in,
                              void* d_out, int out_size, void* d_ws, size_t ws_size,
                              hipStream_t stream) {
    const float* z          = (const float*)d_in[0];
    const int*   edge_index = (const int*)d_in[1];
    const float* W          = (const float*)d_in[2];
    const float* bias       = (const float*)d_in[3];
    float* out = (float*)d_out;

    const int n_nodes = in_sizes[0] / DIM;
    const int n_edges = in_sizes[1] / 2;

    float* zW = (float*)d_ws;  // n_nodes*DIM*4 = 25.6 MB

    const int gemm_blocks = (n_nodes + 63) / 64;
    zw_gemm_kernel<<<gemm_blocks, 256, 0, stream>>>(z, W, zW, n_nodes);

    const int edge_blocks = (n_edges * 16 + 255) / 256;
    edge_score_kernel<<<edge_blocks, 256, 0, stream>>>(zW, z, edge_index, bias,
                                                       out, n_edges);
}

// Round 2
// 151.182 us; speedup vs baseline: 1.3406x; 1.3406x over previous
//
#include <hip/hip_runtime.h>

#define DIM 64
#define ROWS_PER_BLOCK 64
#define ZPAD 68  // 68 dwords/row -> successive rows 16 banks apart (2-way, free)

__device__ __forceinline__ float bf2f_lo(unsigned int u) {
    return __uint_as_float(u << 16);
}
__device__ __forceinline__ float bf2f_hi(unsigned int u) {
    return __uint_as_float(u & 0xFFFF0000u);
}
__device__ __forceinline__ unsigned short f2bf(float f) {
    unsigned int u = __float_as_uint(f);
    u += 0x7FFFu + ((u >> 16) & 1u);  // round-to-nearest-even
    return (unsigned short)(u >> 16);
}
__device__ __forceinline__ void fma4(float4& acc, float a, const float4& w) {
    acc.x = fmaf(a, w.x, acc.x);
    acc.y = fmaf(a, w.y, acc.y);
    acc.z = fmaf(a, w.z, acc.z);
    acc.w = fmaf(a, w.w, acc.w);
}

// Kernel 1: zW = z @ W, emitted as bf16; also emits bf16 copy of z.
// Block = 256 threads = 64 rows; per-thread register tile 4 rows x 4 cols
// -> 16 independent FMA chains (fixes round-1 latency bound).
__global__ __launch_bounds__(256) void zw_gemm_bf16_kernel(
    const float* __restrict__ z, const float* __restrict__ W,
    unsigned short* __restrict__ zw_bf, unsigned short* __restrict__ z_bf,
    int n_nodes) {
    __shared__ float sW[DIM * DIM];
    __shared__ float sZ[ROWS_PER_BLOCK][ZPAD];

    const int tid = threadIdx.x;
    const int rowBase = blockIdx.x * ROWS_PER_BLOCK;

    // Stage W (16 KB) cooperatively.
    {
        const float4* W4 = (const float4*)W;
        float4* sW4 = (float4*)sW;
        for (int i = tid; i < DIM * DIM / 4; i += 256) sW4[i] = W4[i];
    }
    // Stage z tile (64x64 fp32) + emit bf16 copy of z on the way through.
    for (int f = tid; f < ROWS_PER_BLOCK * DIM / 4; f += 256) {
        const int r  = f >> 4;          // row in tile
        const int c4 = (f & 15) * 4;    // col
        const int row = rowBase + r;
        float4 v = make_float4(0.f, 0.f, 0.f, 0.f);
        if (row < n_nodes) {
            v = *(const float4*)(z + (size_t)row * DIM + c4);
            ushort4 h;
            h.x = f2bf(v.x); h.y = f2bf(v.y); h.z = f2bf(v.z); h.w = f2bf(v.w);
            *(ushort4*)(z_bf + (size_t)row * DIM + c4) = h;
        }
        *(float4*)(&sZ[r][c4]) = v;
    }
    __syncthreads();

    const int rg = tid >> 4;   // 0..15 -> 4 rows each
    const int cg = tid & 15;   // 0..15 -> 4 cols each
    const int c  = cg * 4;
    const int r0 = rg * 4;

    float4 acc0 = make_float4(0.f, 0.f, 0.f, 0.f);
    float4 acc1 = acc0, acc2 = acc0, acc3 = acc0;

#pragma unroll
    for (int k = 0; k < DIM; k += 4) {
        // 16 lanes (same k) read 256B contiguous of sW -> conflict-free b128
        float4 w0 = *(const float4*)(&sW[(k + 0) * DIM + c]);
        float4 w1 = *(const float4*)(&sW[(k + 1) * DIM + c]);
        float4 w2 = *(const float4*)(&sW[(k + 2) * DIM + c]);
        float4 w3 = *(const float4*)(&sW[(k + 3) * DIM + c]);
        float4 z0 = *(const float4*)(&sZ[r0 + 0][k]);
        float4 z1 = *(const float4*)(&sZ[r0 + 1][k]);
        float4 z2 = *(const float4*)(&sZ[r0 + 2][k]);
        float4 z3 = *(const float4*)(&sZ[r0 + 3][k]);

        fma4(acc0, z0.x, w0); fma4(acc0, z0.y, w1); fma4(acc0, z0.z, w2); fma4(acc0, z0.w, w3);
        fma4(acc1, z1.x, w0); fma4(acc1, z1.y, w1); fma4(acc1, z1.z, w2); fma4(acc1, z1.w, w3);
        fma4(acc2, z2.x, w0); fma4(acc2, z2.y, w1); fma4(acc2, z2.z, w2); fma4(acc2, z2.w, w3);
        fma4(acc3, z3.x, w0); fma4(acc3, z3.y, w1); fma4(acc3, z3.z, w2); fma4(acc3, z3.w, w3);
    }

    // Store zW as bf16: 16 lanes (cg) per row write 128B contiguous.
    float4 accs[4] = {acc0, acc1, acc2, acc3};
#pragma unroll
    for (int r = 0; r < 4; ++r) {
        const int row = rowBase + r0 + r;
        if (row < n_nodes) {
            ushort4 h;
            h.x = f2bf(accs[r].x); h.y = f2bf(accs[r].y);
            h.z = f2bf(accs[r].z); h.w = f2bf(accs[r].w);
            *(ushort4*)(zw_bf + (size_t)row * DIM + c) = h;
        }
    }
}

// Kernel 2: 8 lanes per edge; each lane loads 16B (8 bf16) of each row.
// One row = 128B = exactly one cache line.
__global__ __launch_bounds__(256) void edge_score_bf16_kernel(
    const unsigned short* __restrict__ zw_bf, const unsigned short* __restrict__ z_bf,
    const int* __restrict__ edge_index, const float* __restrict__ bias,
    float* __restrict__ out, int n_edges) {
    const int t = blockIdx.x * 256 + threadIdx.x;
    const int edge = t >> 3;
    const int sub = t & 7;
    if (edge >= n_edges) return;

    const int src = edge_index[edge];
    const int dst = edge_index[n_edges + edge];

    uint4 a = ((const uint4*)(zw_bf + (size_t)src * DIM))[sub];
    uint4 b = ((const uint4*)(z_bf  + (size_t)dst * DIM))[sub];

    float p = 0.f;
    p = fmaf(bf2f_lo(a.x), bf2f_lo(b.x), p);
    p = fmaf(bf2f_hi(a.x), bf2f_hi(b.x), p);
    p = fmaf(bf2f_lo(a.y), bf2f_lo(b.y), p);
    p = fmaf(bf2f_hi(a.y), bf2f_hi(b.y), p);
    p = fmaf(bf2f_lo(a.z), bf2f_lo(b.z), p);
    p = fmaf(bf2f_hi(a.z), bf2f_hi(b.z), p);
    p = fmaf(bf2f_lo(a.w), bf2f_lo(b.w), p);
    p = fmaf(bf2f_hi(a.w), bf2f_hi(b.w), p);

    // reduce within the 8-lane group
    p += __shfl_xor(p, 1);
    p += __shfl_xor(p, 2);
    p += __shfl_xor(p, 4);

    if (sub == 0) out[edge] = p + bias[0];
}

extern "C" void kernel_launch(void* const* d_in, const int* in_sizes, int n_in,
                              void* d_out, int out_size, void* d_ws, size_t ws_size,
                              hipStream_t stream) {
    const float* z          = (const float*)d_in[0];
    const int*   edge_index = (const int*)d_in[1];
    const float* W          = (const float*)d_in[2];
    const float* bias       = (const float*)d_in[3];
    float* out = (float*)d_out;

    const int n_nodes = in_sizes[0] / DIM;
    const int n_edges = in_sizes[1] / 2;

    unsigned short* zw_bf = (unsigned short*)d_ws;                      // 12.8 MB
    unsigned short* z_bf  = zw_bf + (size_t)n_nodes * DIM;              // 12.8 MB

    const int gemm_blocks = (n_nodes + ROWS_PER_BLOCK - 1) / ROWS_PER_BLOCK;
    zw_gemm_bf16_kernel<<<gemm_blocks, 256, 0, stream>>>(z, W, zw_bf, z_bf, n_nodes);

    const int edge_blocks = (n_edges * 8 + 255) / 256;
    edge_score_bf16_kernel<<<edge_blocks, 256, 0, stream>>>(zw_bf, z_bf, edge_index,
                                                            bias, out, n_edges);
}

// Round 3
// 116.703 us; speedup vs baseline: 1.7367x; 1.2954x over previous
//
#include <hip/hip_runtime.h>

#define DIM 64
#define ROWS 64          // rows per block (kernel 1)
#define LROW 72          // padded LDS row stride in bf16 (144 B) -> conflict-free b128 frags

typedef __attribute__((ext_vector_type(8))) short bf16x8;
typedef __attribute__((ext_vector_type(4))) float f32x4;

__device__ __forceinline__ unsigned short f2bf(float f) {
    unsigned int u = __float_as_uint(f);
    u += 0x7FFFu + ((u >> 16) & 1u);  // round-to-nearest-even
    return (unsigned short)(u >> 16);
}
__device__ __forceinline__ float bf2f_lo(unsigned int u) {
    return __uint_as_float(u << 16);
}
__device__ __forceinline__ float bf2f_hi(unsigned int u) {
    return __uint_as_float(u & 0xFFFF0000u);
}

// Kernel 1: zW = z @ W via bf16 MFMA; emits bf16 zW and bf16 copy of z.
// Block = 256 thr = 4 waves = 64 rows. Wave w owns rows [w*16, w*16+16).
// MFMA 16x16x32: A[m][k] m=lane&15, k=quad*8+j; B[k][n] n=lane&15, k=quad*8+j;
// C/D: col=lane&15, row=quad*4+reg.
__global__ __launch_bounds__(256) void zw_gemm_mfma_kernel(
    const float* __restrict__ z, const float* __restrict__ W,
    unsigned short* __restrict__ zw_bf, unsigned short* __restrict__ z_bf,
    int n_nodes) {
    __shared__ unsigned short sZ[ROWS * LROW];   // z tile, bf16, padded rows
    __shared__ unsigned short sWt[DIM * LROW];   // W^T, bf16: sWt[n][k]

    const int tid = threadIdx.x;
    const int rowBase = blockIdx.x * ROWS;

    // ---- stage z tile (fp32 -> bf16) + write z_bf out ----
    for (int f = tid; f < ROWS * 16; f += 256) {
        const int r  = f >> 4;
        const int c4 = (f & 15) * 4;
        const int row = rowBase + r;
        float4 v = make_float4(0.f, 0.f, 0.f, 0.f);
        if (row < n_nodes) v = *(const float4*)(z + (size_t)row * DIM + c4);
        ushort4 h;
        h.x = f2bf(v.x); h.y = f2bf(v.y); h.z = f2bf(v.z); h.w = f2bf(v.w);
        *(ushort4*)(&sZ[r * LROW + c4]) = h;
        if (row < n_nodes) *(ushort4*)(z_bf + (size_t)row * DIM + c4) = h;
    }
    // ---- stage W transposed as bf16: sWt[n*LROW + k] = bf16(W[k*64+n]) ----
    for (int f = tid; f < DIM * DIM; f += 256) {
        const int n = f & 63;        // fastest -> coalesced global read
        const int k = f >> 6;
        sWt[n * LROW + k] = f2bf(W[f]);
    }
    __syncthreads();

    const int wave = tid >> 6;
    const int lane = tid & 63;
    const int m    = lane & 15;
    const int quad = lane >> 4;

    // A fragments for this wave's 16 rows, k in [0,32) and [32,64)
    const unsigned short* aBase = &sZ[(wave * 16 + m) * LROW + quad * 8];
    bf16x8 a0 = *(const bf16x8*)(aBase);
    bf16x8 a1 = *(const bf16x8*)(aBase + 32);

    f32x4 acc[4];
#pragma unroll
    for (int t = 0; t < 4; ++t) {
        const unsigned short* bBase = &sWt[(t * 16 + m) * LROW + quad * 8];
        bf16x8 b0 = *(const bf16x8*)(bBase);
        bf16x8 b1 = *(const bf16x8*)(bBase + 32);
        f32x4 c = {0.f, 0.f, 0.f, 0.f};
        c = __builtin_amdgcn_mfma_f32_16x16x32_bf16(a0, b0, c, 0, 0, 0);
        c = __builtin_amdgcn_mfma_f32_16x16x32_bf16(a1, b1, c, 0, 0, 0);
        acc[t] = c;
    }

    // Epilogue: C/D col = m, row = quad*4 + r. Store zW as bf16.
#pragma unroll
    for (int t = 0; t < 4; ++t) {
#pragma unroll
        for (int r = 0; r < 4; ++r) {
            const int row = rowBase + wave * 16 + quad * 4 + r;
            if (row < n_nodes)
                zw_bf[(size_t)row * DIM + t * 16 + m] = f2bf(acc[t][r]);
        }
    }
}

// Kernel 2: 8 lanes per edge; each lane loads 16B (8 bf16) of each 128B row.
__global__ __launch_bounds__(256) void edge_score_bf16_kernel(
    const unsigned short* __restrict__ zw_bf, const unsigned short* __restrict__ z_bf,
    const int* __restrict__ edge_index, const float* __restrict__ bias,
    float* __restrict__ out, int n_edges) {
    const int t = blockIdx.x * 256 + threadIdx.x;
    const int edge = t >> 3;
    const int sub = t & 7;
    if (edge >= n_edges) return;

    const int src = edge_index[edge];
    const int dst = edge_index[n_edges + edge];

    uint4 a = ((const uint4*)(zw_bf + (size_t)src * DIM))[sub];
    uint4 b = ((const uint4*)(z_bf  + (size_t)dst * DIM))[sub];

    float p = 0.f;
    p = fmaf(bf2f_lo(a.x), bf2f_lo(b.x), p);
    p = fmaf(bf2f_hi(a.x), bf2f_hi(b.x), p);
    p = fmaf(bf2f_lo(a.y), bf2f_lo(b.y), p);
    p = fmaf(bf2f_hi(a.y), bf2f_hi(b.y), p);
    p = fmaf(bf2f_lo(a.z), bf2f_lo(b.z), p);
    p = fmaf(bf2f_hi(a.z), bf2f_hi(b.z), p);
    p = fmaf(bf2f_lo(a.w), bf2f_lo(b.w), p);
    p = fmaf(bf2f_hi(a.w), bf2f_hi(b.w), p);

    p += __shfl_xor(p, 1);
    p += __shfl_xor(p, 2);
    p += __shfl_xor(p, 4);

    if (sub == 0) out[edge] = p + bias[0];
}

extern "C" void kernel_launch(void* const* d_in, const int* in_sizes, int n_in,
                              void* d_out, int out_size, void* d_ws, size_t ws_size,
                              hipStream_t stream) {
    const float* z          = (const float*)d_in[0];
    const int*   edge_index = (const int*)d_in[1];
    const float* W          = (const float*)d_in[2];
    const float* bias       = (const float*)d_in[3];
    float* out = (float*)d_out;

    const int n_nodes = in_sizes[0] / DIM;
    const int n_edges = in_sizes[1] / 2;

    unsigned short* zw_bf = (unsigned short*)d_ws;                 // 12.8 MB
    unsigned short* z_bf  = zw_bf + (size_t)n_nodes * DIM;         // 12.8 MB

    const int gemm_blocks = (n_nodes + ROWS - 1) / ROWS;
    zw_gemm_mfma_kernel<<<gemm_blocks, 256, 0, stream>>>(z, W, zw_bf, z_bf, n_nodes);

    const int edge_blocks = (n_edges * 8 + 255) / 256;
    edge_score_bf16_kernel<<<edge_blocks, 256, 0, stream>>>(zw_bf, z_bf, edge_index,
                                                            bias, out, n_edges);
}

// Round 4
// 115.263 us; speedup vs baseline: 1.7584x; 1.0125x over previous
//
#include <hip/hip_runtime.h>

#define DIM 64
#define ROWS 64          // rows per block (kernel 1)
#define LROW 72          // padded LDS row stride in bf16 (144 B) -> conflict-free b128 frags

typedef __attribute__((ext_vector_type(8))) short bf16x8;
typedef __attribute__((ext_vector_type(4))) float f32x4;

__device__ __forceinline__ unsigned short f2bf(float f) {
    unsigned int u = __float_as_uint(f);
    u += 0x7FFFu + ((u >> 16) & 1u);  // round-to-nearest-even
    return (unsigned short)(u >> 16);
}
__device__ __forceinline__ float bf2f_lo(unsigned int u) {
    return __uint_as_float(u << 16);
}
__device__ __forceinline__ float bf2f_hi(unsigned int u) {
    return __uint_as_float(u & 0xFFFF0000u);
}
__device__ __forceinline__ float dot8_bf16(uint4 a, uint4 b) {
    float p = 0.f;
    p = fmaf(bf2f_lo(a.x), bf2f_lo(b.x), p);
    p = fmaf(bf2f_hi(a.x), bf2f_hi(b.x), p);
    p = fmaf(bf2f_lo(a.y), bf2f_lo(b.y), p);
    p = fmaf(bf2f_hi(a.y), bf2f_hi(b.y), p);
    p = fmaf(bf2f_lo(a.z), bf2f_lo(b.z), p);
    p = fmaf(bf2f_hi(a.z), bf2f_hi(b.z), p);
    p = fmaf(bf2f_lo(a.w), bf2f_lo(b.w), p);
    p = fmaf(bf2f_hi(a.w), bf2f_hi(b.w), p);
    return p;
}
__device__ __forceinline__ float red8(float p) {
    p += __shfl_xor(p, 1);
    p += __shfl_xor(p, 2);
    p += __shfl_xor(p, 4);
    return p;
}

// Kernel 1: zW = z @ W via bf16 MFMA; emits bf16 zW and bf16 copy of z.
__global__ __launch_bounds__(256) void zw_gemm_mfma_kernel(
    const float* __restrict__ z, const float* __restrict__ W,
    unsigned short* __restrict__ zw_bf, unsigned short* __restrict__ z_bf,
    int n_nodes) {
    __shared__ unsigned short sZ[ROWS * LROW];   // z tile, bf16, padded rows
    __shared__ unsigned short sWt[DIM * LROW];   // W^T, bf16: sWt[n][k]

    const int tid = threadIdx.x;
    const int rowBase = blockIdx.x * ROWS;

    // ---- stage z tile (fp32 -> bf16) + write z_bf out ----
    for (int f = tid; f < ROWS * 16; f += 256) {
        const int r  = f >> 4;
        const int c4 = (f & 15) * 4;
        const int row = rowBase + r;
        float4 v = make_float4(0.f, 0.f, 0.f, 0.f);
        if (row < n_nodes) v = *(const float4*)(z + (size_t)row * DIM + c4);
        ushort4 h;
        h.x = f2bf(v.x); h.y = f2bf(v.y); h.z = f2bf(v.z); h.w = f2bf(v.w);
        *(ushort4*)(&sZ[r * LROW + c4]) = h;
        if (row < n_nodes) *(ushort4*)(z_bf + (size_t)row * DIM + c4) = h;
    }
    // ---- stage W transposed as bf16: sWt[n*LROW + k] = bf16(W[k*64+n]) ----
    for (int f = tid; f < DIM * DIM; f += 256) {
        const int n = f & 63;        // fastest -> coalesced global read
        const int k = f >> 6;
        sWt[n * LROW + k] = f2bf(W[f]);
    }
    __syncthreads();

    const int wave = tid >> 6;
    const int lane = tid & 63;
    const int m    = lane & 15;
    const int quad = lane >> 4;

    const unsigned short* aBase = &sZ[(wave * 16 + m) * LROW + quad * 8];
    bf16x8 a0 = *(const bf16x8*)(aBase);
    bf16x8 a1 = *(const bf16x8*)(aBase + 32);

    f32x4 acc[4];
#pragma unroll
    for (int t = 0; t < 4; ++t) {
        const unsigned short* bBase = &sWt[(t * 16 + m) * LROW + quad * 8];
        bf16x8 b0 = *(const bf16x8*)(bBase);
        bf16x8 b1 = *(const bf16x8*)(bBase + 32);
        f32x4 c = {0.f, 0.f, 0.f, 0.f};
        c = __builtin_amdgcn_mfma_f32_16x16x32_bf16(a0, b0, c, 0, 0, 0);
        c = __builtin_amdgcn_mfma_f32_16x16x32_bf16(a1, b1, c, 0, 0, 0);
        acc[t] = c;
    }

#pragma unroll
    for (int t = 0; t < 4; ++t) {
#pragma unroll
        for (int r = 0; r < 4; ++r) {
            const int row = rowBase + wave * 16 + quad * 4 + r;
            if (row < n_nodes)
                zw_bf[(size_t)row * DIM + t * 16 + m] = f2bf(acc[t][r]);
        }
    }
}

// Kernel 2: 4 edges per 8-lane group.  Two broadcast int4 index loads, then
// 8 independent 16B gathers in flight (4x the MLP of round 2), unpack+fma,
// 3-step shfl reduce, 4-lane coalesced store.
__global__ __launch_bounds__(256) void edge_score_bf16_kernel(
    const unsigned short* __restrict__ zw_bf, const unsigned short* __restrict__ z_bf,
    const int* __restrict__ edge_index, const float* __restrict__ bias,
    float* __restrict__ out, int n_edges) {
    const int tid = blockIdx.x * 256 + threadIdx.x;
    const int group = tid >> 3;
    const int sub = tid & 7;
    const int e0 = group * 4;
    if (e0 >= n_edges) return;

    const float bias0 = bias[0];

    if (e0 + 3 < n_edges) {
        int4 srcs = *(const int4*)(edge_index + e0);
        int4 dsts = *(const int4*)(edge_index + n_edges + e0);

        // 8 independent gathers issued back-to-back
        uint4 a0 = ((const uint4*)(zw_bf + (size_t)srcs.x * DIM))[sub];
        uint4 a1 = ((const uint4*)(zw_bf + (size_t)srcs.y * DIM))[sub];
        uint4 a2 = ((const uint4*)(zw_bf + (size_t)srcs.z * DIM))[sub];
        uint4 a3 = ((const uint4*)(zw_bf + (size_t)srcs.w * DIM))[sub];
        uint4 b0 = ((const uint4*)(z_bf + (size_t)dsts.x * DIM))[sub];
        uint4 b1 = ((const uint4*)(z_bf + (size_t)dsts.y * DIM))[sub];
        uint4 b2 = ((const uint4*)(z_bf + (size_t)dsts.z * DIM))[sub];
        uint4 b3 = ((const uint4*)(z_bf + (size_t)dsts.w * DIM))[sub];

        float p0 = red8(dot8_bf16(a0, b0));
        float p1 = red8(dot8_bf16(a1, b1));
        float p2 = red8(dot8_bf16(a2, b2));
        float p3 = red8(dot8_bf16(a3, b3));

        // lane sub (0..3) writes edge e0+sub -> contiguous 4-float chunk/group
        float v = (sub & 1) ? ((sub & 2) ? p3 : p1) : ((sub & 2) ? p2 : p0);
        if (sub < 4) out[e0 + sub] = v + bias0;
    } else {
        for (int e = e0; e < n_edges; ++e) {
            const int src = edge_index[e];
            const int dst = edge_index[n_edges + e];
            uint4 a = ((const uint4*)(zw_bf + (size_t)src * DIM))[sub];
            uint4 b = ((const uint4*)(z_bf + (size_t)dst * DIM))[sub];
            float p = red8(dot8_bf16(a, b));
            if (sub == 0) out[e] = p + bias0;
        }
    }
}

extern "C" void kernel_launch(void* const* d_in, const int* in_sizes, int n_in,
                              void* d_out, int out_size, void* d_ws, size_t ws_size,
                              hipStream_t stream) {
    const float* z          = (const float*)d_in[0];
    const int*   edge_index = (const int*)d_in[1];
    const float* W          = (const float*)d_in[2];
    const float* bias       = (const float*)d_in[3];
    float* out = (float*)d_out;

    const int n_nodes = in_sizes[0] / DIM;
    const int n_edges = in_sizes[1] / 2;

    unsigned short* zw_bf = (unsigned short*)d_ws;                 // 12.8 MB
    unsigned short* z_bf  = zw_bf + (size_t)n_nodes * DIM;         // 12.8 MB

    const int gemm_blocks = (n_nodes + ROWS - 1) / ROWS;
    zw_gemm_mfma_kernel<<<gemm_blocks, 256, 0, stream>>>(z, W, zw_bf, z_bf, n_nodes);

    // 256 threads = 32 groups x 4 edges = 128 edges per block
    const int edge_blocks = (n_edges + 127) / 128;
    edge_score_bf16_kernel<<<edge_blocks, 256, 0, stream>>>(zw_bf, z_bf, edge_index,
                                                            bias, out, n_edges);
}

// Round 5
// 115.038 us; speedup vs baseline: 1.7618x; 1.0020x over previous
//
#include <hip/hip_runtime.h>

#define DIM 64
#define ROWS 64          // rows per block (kernel 1)
#define LROW 72          // sWt padded row stride (shorts): 144 B, 16B-aligned frags
#define EPAD 72          // epilogue padded row stride (shorts)

typedef __attribute__((ext_vector_type(8))) short bf16x8;
typedef __attribute__((ext_vector_type(4))) float f32x4;

__device__ __forceinline__ unsigned short f2bf(float f) {
    unsigned int u = __float_as_uint(f);
    u += 0x7FFFu + ((u >> 16) & 1u);  // round-to-nearest-even
    return (unsigned short)(u >> 16);
}
__device__ __forceinline__ float bf2f_lo(unsigned int u) {
    return __uint_as_float(u << 16);
}
__device__ __forceinline__ float bf2f_hi(unsigned int u) {
    return __uint_as_float(u & 0xFFFF0000u);
}
__device__ __forceinline__ float dot8_bf16(uint4 a, uint4 b) {
    float p = 0.f;
    p = fmaf(bf2f_lo(a.x), bf2f_lo(b.x), p);
    p = fmaf(bf2f_hi(a.x), bf2f_hi(b.x), p);
    p = fmaf(bf2f_lo(a.y), bf2f_lo(b.y), p);
    p = fmaf(bf2f_hi(a.y), bf2f_hi(b.y), p);
    p = fmaf(bf2f_lo(a.z), bf2f_lo(b.z), p);
    p = fmaf(bf2f_hi(a.z), bf2f_hi(b.z), p);
    p = fmaf(bf2f_lo(a.w), bf2f_lo(b.w), p);
    p = fmaf(bf2f_hi(a.w), bf2f_hi(b.w), p);
    return p;
}
__device__ __forceinline__ float red8(float p) {
    p += __shfl_xor(p, 1);
    p += __shfl_xor(p, 2);
    p += __shfl_xor(p, 4);
    return p;
}

// Kernel 1 (v3): zW = z @ W via bf16 MFMA.
// Changes vs v2: A-fragments loaded DIRECTLY from global z (no sZ LDS
// round-trip; z_bf emitted from the same registers), and the epilogue is
// repacked through LDS so zW stores are 2 x 16B/lane (16 full 64B lines
// per store instruction) instead of 16 x 2B/lane scattered stores.
__global__ __launch_bounds__(256) void zw_gemm_mfma_kernel(
    const float* __restrict__ z, const float* __restrict__ W,
    unsigned short* __restrict__ zw_bf, unsigned short* __restrict__ z_bf,
    int n_nodes) {
    __shared__ unsigned short sWt[DIM * LROW];       // W^T bf16: sWt[n][k]
    __shared__ unsigned short sEpi[4 * 16 * EPAD];   // per-wave epilogue slab

    const int tid  = threadIdx.x;
    const int wave = tid >> 6;
    const int lane = tid & 63;
    const int m    = lane & 15;
    const int quad = lane >> 4;
    const int rowBase = blockIdx.x * ROWS;

    // ---- stage W transposed as bf16: sWt[n*LROW + k] = bf16(W[k*64+n]) ----
    for (int f = tid; f < DIM * DIM; f += 256) {
        const int n = f & 63;        // fastest -> coalesced global read
        const int k = f >> 6;
        sWt[n * LROW + k] = f2bf(W[f]);
    }

    // ---- A-fragments directly from global z (row m, cols quad*8..+8 and +32) ----
    const int row = rowBase + wave * 16 + m;
    bf16x8 a0 = {0, 0, 0, 0, 0, 0, 0, 0};
    bf16x8 a1 = {0, 0, 0, 0, 0, 0, 0, 0};
    if (row < n_nodes) {
        const float* zr = z + (size_t)row * DIM + quad * 8;
        float4 v0 = *(const float4*)(zr);
        float4 v1 = *(const float4*)(zr + 4);
        float4 v2 = *(const float4*)(zr + 32);
        float4 v3 = *(const float4*)(zr + 36);
        a0[0] = (short)f2bf(v0.x); a0[1] = (short)f2bf(v0.y);
        a0[2] = (short)f2bf(v0.z); a0[3] = (short)f2bf(v0.w);
        a0[4] = (short)f2bf(v1.x); a0[5] = (short)f2bf(v1.y);
        a0[6] = (short)f2bf(v1.z); a0[7] = (short)f2bf(v1.w);
        a1[0] = (short)f2bf(v2.x); a1[1] = (short)f2bf(v2.y);
        a1[2] = (short)f2bf(v2.z); a1[3] = (short)f2bf(v2.w);
        a1[4] = (short)f2bf(v3.x); a1[5] = (short)f2bf(v3.y);
        a1[6] = (short)f2bf(v3.z); a1[7] = (short)f2bf(v3.w);
        // emit bf16 copy of z from the same registers (16B aligned stores)
        *(bf16x8*)(z_bf + (size_t)row * DIM + quad * 8)      = a0;
        *(bf16x8*)(z_bf + (size_t)row * DIM + 32 + quad * 8) = a1;
    }
    __syncthreads();   // sWt ready

    f32x4 acc[4];
#pragma unroll
    for (int t = 0; t < 4; ++t) {
        const unsigned short* bBase = &sWt[(t * 16 + m) * LROW + quad * 8];
        bf16x8 b0 = *(const bf16x8*)(bBase);
        bf16x8 b1 = *(const bf16x8*)(bBase + 32);
        f32x4 c = {0.f, 0.f, 0.f, 0.f};
        c = __builtin_amdgcn_mfma_f32_16x16x32_bf16(a0, b0, c, 0, 0, 0);
        c = __builtin_amdgcn_mfma_f32_16x16x32_bf16(a1, b1, c, 0, 0, 0);
        acc[t] = c;
    }

    // ---- epilogue: repack via LDS, then 2 x 16B/lane coalesced stores ----
    unsigned short* ep = &sEpi[wave * 16 * EPAD];
#pragma unroll
    for (int t = 0; t < 4; ++t) {
#pragma unroll
        for (int r = 0; r < 4; ++r) {
            // C/D: col = t*16+m, row = quad*4+r  (2-way bank alias: free)
            ep[(quad * 4 + r) * EPAD + t * 16 + m] = f2bf(acc[t][r]);
        }
    }
    __syncthreads();   // epilogue slabs ready
    {
        const int r = lane >> 2;   // 0..15: local row
        const int s = lane & 3;
        const int grow = rowBase + wave * 16 + r;
#pragma unroll
        for (int h = 0; h < 2; ++h) {
            const int seg = h * 4 + s;   // 0..7: 8-short (16B) segment
            if (grow < n_nodes) {
                bf16x8 v = *(const bf16x8*)(&ep[r * EPAD + seg * 8]);
                *(bf16x8*)(zw_bf + (size_t)grow * DIM + seg * 8) = v;
            }
        }
    }
}

// Kernel 2: 4 edges per 8-lane group (unchanged from round 4).
__global__ __launch_bounds__(256) void edge_score_bf16_kernel(
    const unsigned short* __restrict__ zw_bf, const unsigned short* __restrict__ z_bf,
    const int* __restrict__ edge_index, const float* __restrict__ bias,
    float* __restrict__ out, int n_edges) {
    const int tid = blockIdx.x * 256 + threadIdx.x;
    const int group = tid >> 3;
    const int sub = tid & 7;
    const int e0 = group * 4;
    if (e0 >= n_edges) return;

    const float bias0 = bias[0];

    if (e0 + 3 < n_edges) {
        int4 srcs = *(const int4*)(edge_index + e0);
        int4 dsts = *(const int4*)(edge_index + n_edges + e0);

        uint4 a0 = ((const uint4*)(zw_bf + (size_t)srcs.x * DIM))[sub];
        uint4 a1 = ((const uint4*)(zw_bf + (size_t)srcs.y * DIM))[sub];
        uint4 a2 = ((const uint4*)(zw_bf + (size_t)srcs.z * DIM))[sub];
        uint4 a3 = ((const uint4*)(zw_bf + (size_t)srcs.w * DIM))[sub];
        uint4 b0 = ((const uint4*)(z_bf + (size_t)dsts.x * DIM))[sub];
        uint4 b1 = ((const uint4*)(z_bf + (size_t)dsts.y * DIM))[sub];
        uint4 b2 = ((const uint4*)(z_bf + (size_t)dsts.z * DIM))[sub];
        uint4 b3 = ((const uint4*)(z_bf + (size_t)dsts.w * DIM))[sub];

        float p0 = red8(dot8_bf16(a0, b0));
        float p1 = red8(dot8_bf16(a1, b1));
        float p2 = red8(dot8_bf16(a2, b2));
        float p3 = red8(dot8_bf16(a3, b3));

        float v = (sub & 1) ? ((sub & 2) ? p3 : p1) : ((sub & 2) ? p2 : p0);
        if (sub < 4) out[e0 + sub] = v + bias0;
    } else {
        for (int e = e0; e < n_edges; ++e) {
            const int src = edge_index[e];
            const int dst = edge_index[n_edges + e];
            uint4 a = ((const uint4*)(zw_bf + (size_t)src * DIM))[sub];
            uint4 b = ((const uint4*)(z_bf + (size_t)dst * DIM))[sub];
            float p = red8(dot8_bf16(a, b));
            if (sub == 0) out[e] = p + bias0;
        }
    }
}

extern "C" void kernel_launch(void* const* d_in, const int* in_sizes, int n_in,
                              void* d_out, int out_size, void* d_ws, size_t ws_size,
                              hipStream_t stream) {
    const float* z          = (const float*)d_in[0];
    const int*   edge_index = (const int*)d_in[1];
    const float* W          = (const float*)d_in[2];
    const float* bias       = (const float*)d_in[3];
    float* out = (float*)d_out;

    const int n_nodes = in_sizes[0] / DIM;
    const int n_edges = in_sizes[1] / 2;

    unsigned short* zw_bf = (unsigned short*)d_ws;                 // 12.8 MB
    unsigned short* z_bf  = zw_bf + (size_t)n_nodes * DIM;         // 12.8 MB

    const int gemm_blocks = (n_nodes + ROWS - 1) / ROWS;
    zw_gemm_mfma_kernel<<<gemm_blocks, 256, 0, stream>>>(z, W, zw_bf, z_bf, n_nodes);

    const int edge_blocks = (n_edges + 127) / 128;
    edge_score_bf16_kernel<<<edge_blocks, 256, 0, stream>>>(zw_bf, z_bf, edge_index,
                                                            bias, out, n_edges);
}